// Round 1
// 145.080 us; speedup vs baseline: 1.0319x; 1.0319x over previous
//
#include <hip/hip_runtime.h>

#define NPTS 65536
#define CCH  32
#define DDIM 64
#define GVOX (DDIM*DDIM*DDIM)   // B=1 -> 262144 voxels
#define MAXTILES 4128           // >= 65536/16 + 27 (per-class padding)

typedef _Float16 half8  __attribute__((ext_vector_type(8)));
typedef _Float16 half4v __attribute__((ext_vector_type(4)));
typedef float    floatx4 __attribute__((ext_vector_type(4)));

// ---------------- prep0: init + dtype conversion (one launch) ----------------
// ranges: map init | sorted init | values->f16 | weight transpose | zero rows | counters
__global__ __launch_bounds__(256) void k_prep0(
    int* __restrict__ map, int* __restrict__ sorted,
    const float* __restrict__ values, _Float16* __restrict__ valsh,
    const float* __restrict__ k1, const float* __restrict__ k2,
    _Float16* __restrict__ w1, _Float16* __restrict__ w2,
    _Float16* __restrict__ hh, int* __restrict__ pcoord,
    int* __restrict__ cnt, int* __restrict__ slot)
{
  int tid = blockIdx.x * 256 + threadIdx.x;
  if (tid < GVOX/4) { ((int4*)map)[tid] = make_int4(-1,-1,-1,-1); return; }
  tid -= GVOX/4;
  if (tid < MAXTILES*16) { sorted[tid] = NPTS; return; }
  tid -= MAXTILES*16;
  if (tid < (NPTS*CCH)/4) {
    float4 v = ((const float4*)values)[tid];
    half4v h = { (_Float16)v.x, (_Float16)v.y, (_Float16)v.z, (_Float16)v.w };
    ((half4v*)valsh)[tid] = h; return;
  }
  tid -= (NPTS*CCH)/4;
  if (tid < 27*CCH*CCH) {                       // (t,cin,cout) f32 -> (t,cout,cin) f16
    int t = tid/(CCH*CCH), r = tid%(CCH*CCH);
    int cin = r/CCH, cout = r%CCH;
    int o = (t*CCH + cout)*CCH + cin;
    w1[o] = (_Float16)k1[tid]; w2[o] = (_Float16)k2[tid]; return;
  }
  tid -= 27*CCH*CCH;
  if (tid < CCH) { valsh[NPTS*CCH+tid] = (_Float16)0.f; hh[NPTS*CCH+tid] = (_Float16)0.f; return; }
  tid -= CCH;
  if (tid < 27) { cnt[tid] = 0; slot[tid] = 0; return; }
  tid -= 27;
  if (tid == 0) pcoord[NPTS] = 0;               // sentinel point coords
}
#define PREP0_THREADS (GVOX/4 + MAXTILES*16 + (NPTS*CCH)/4 + 27*CCH*CCH + CCH + 27 + 1)

// ---------------- prep1: map + pcoord + class histogram ----------------
__global__ __launch_bounds__(256) void k_prep1(const int* __restrict__ idx,
                                               int* __restrict__ map,
                                               int* __restrict__ pcoord,
                                               int* __restrict__ cls,
                                               int* __restrict__ cnt)
{
  __shared__ int lcnt[27];
  if (threadIdx.x < 27) lcnt[threadIdx.x] = 0;
  __syncthreads();
  const int n = blockIdx.x*256 + threadIdx.x;
  const int4 v = ((const int4*)idx)[n];
  const int b = v.x, z = v.y, y = v.z, x = v.w;
  map[((b*DDIM + z)*DDIM + y)*DDIM + x] = n;
  pcoord[n] = (b<<18) | (z<<12) | (y<<6) | x;
  const int cz = (z==0)?0:((z==DDIM-1)?2:1);
  const int cy = (y==0)?0:((y==DDIM-1)?2:1);
  const int cx = (x==0)?0:((x==DDIM-1)?2:1);
  const int c = cz*9 + cy*3 + cx;
  cls[n] = c;
  atomicAdd(&lcnt[c], 1);
  __syncthreads();
  if (threadIdx.x < 27 && lcnt[threadIdx.x]) atomicAdd(&cnt[threadIdx.x], lcnt[threadIdx.x]);
}

// ---------------- prep3: per-block 27-class scan (replaces prep2) +
//                  scatter into class-sorted order + tile class table ---------
__global__ __launch_bounds__(256) void k_prep3(const int* __restrict__ cls,
                                               const int* __restrict__ cnt,
                                               int* __restrict__ slot,
                                               int* __restrict__ sorted,
                                               int* __restrict__ tileclass,
                                               int* __restrict__ ntiles)
{
  __shared__ int s_clsbase[27];
  __shared__ int s_tstart[28];
  if (threadIdx.x == 0) {
    int b = 0, tb = 0;
#pragma unroll
    for (int c = 0; c < 27; ++c) {
      s_clsbase[c] = b; s_tstart[c] = tb;
      const int ntc = (cnt[c] + 15) >> 4;
      b += ntc << 4; tb += ntc;
    }
    s_tstart[27] = tb;
    if (blockIdx.x == 0) *ntiles = tb;
  }
  __syncthreads();

  if (blockIdx.x < NPTS/256) {
    __shared__ int lcnt[27], lbase[27];
    if (threadIdx.x < 27) lcnt[threadIdx.x] = 0;
    __syncthreads();
    const int n = blockIdx.x*256 + threadIdx.x;
    const int c = cls[n];
    const int lrank = atomicAdd(&lcnt[c], 1);
    __syncthreads();
    if (threadIdx.x < 27)
      lbase[threadIdx.x] = lcnt[threadIdx.x] ? atomicAdd(&slot[threadIdx.x], lcnt[threadIdx.x]) : 0;
    __syncthreads();
    sorted[s_clsbase[c] + lbase[c] + lrank] = n;
  } else {
    const int i = (blockIdx.x - NPTS/256)*256 + threadIdx.x;
    if (i >= MAXTILES) return;
    const int nt = s_tstart[27];
    int c = 13;
    if (i < nt) {
      for (int cc = 0; cc < 27; ++cc)
        if (i >= s_tstart[cc] && i < s_tstart[cc+1]) { c = cc; break; }
    }
    tileclass[i] = c;
  }
}

// ---------------- unified gather-MFMA conv, tap-split across 2 waves ---------
// Wave pair per tile: half=0 accumulates taps [0,14), half=1 taps [14,27).
// half=0 dumps partials to LDS; half=1 adds them and runs the epilogue.
// Each wave prefetches all its map results into registers first so the
// map->A->MFMA chain pipelines instead of serializing 27 deep.
template<int J0, int J1>
__device__ __forceinline__ void accum_taps(
    const _Float16* __restrict__ A, const int* __restrict__ map,
    const _Float16* __restrict__ WT,
    int cz, int cy, int cx, int linb,
    const int* az, const int* ay, const int* ax,
    int m, int quad, floatx4& acc0, floatx4& acc1)
{
  int srcs[J1 - J0];
#pragma unroll
  for (int j = J0; j < J1; ++j) {
    const int jz = j/9, jy = (j/3)%3, jx = j%3;
    const int s = map[linb | az[jz] | ay[jy] | ax[jx]];
    srcs[j - J0] = (s < 0) ? (NPTS*CCH) : (s*CCH);   // empty voxel -> zero row
  }
#pragma unroll
  for (int j = J0; j < J1; ++j) {
    const int jz = j/9, jy = (j/3)%3, jx = j%3;
    // per-dim tap index given class (jz/jy/jx compile-time, class wave-uniform)
    const int tz = (cz==1) ? (2-jz) : ((jz==1) ? 1 : ((cz==0) ? 0 : 2));
    const int ty = (cy==1) ? (2-jy) : ((jy==1) ? 1 : ((cy==0) ? 0 : 2));
    const int tx = (cx==1) ? (2-jx) : ((jx==1) ? 1 : ((cx==0) ? 0 : 2));
    const int t  = tz*9 + ty*3 + tx;
    half8 a  = *(const half8*)(A + srcs[j - J0] + quad*8);
    const _Float16* wr = WT + t*(CCH*CCH);
    half8 b0 = *(const half8*)(wr + m*CCH + quad*8);
    half8 b1 = *(const half8*)(wr + (16+m)*CCH + quad*8);
    acc0 = __builtin_amdgcn_mfma_f32_16x16x32_f16(a, b0, acc0, 0, 0, 0);
    acc1 = __builtin_amdgcn_mfma_f32_16x16x32_f16(a, b1, acc1, 0, 0, 0);
  }
}

template<int MODE>
__global__ __launch_bounds__(256) void conv_mfma(
    const _Float16* __restrict__ A,        // (NPTS+1) x 32 f16, row NPTS = zeros
    const int* __restrict__ map,
    const int* __restrict__ pcoord,
    const int* __restrict__ sorted,
    const int* __restrict__ tileclass,
    const int* __restrict__ ntp,
    const _Float16* __restrict__ WT,       // 27 x cout x cin f16
    const float* __restrict__ bias,
    const float* __restrict__ mask,
    const float* __restrict__ resid,
    _Float16* __restrict__ hout,
    float* __restrict__ fout)
{
  __shared__ float red[2][16][33];         // stride 33 breaks quad bank aliasing
  const int wv   = threadIdx.x >> 6;       // 0..3
  const int tl   = wv >> 1;                // tile slot within block
  const int half = wv & 1;                 // tap-half
  const int tile = blockIdx.x*2 + tl;
  const int nt   = *ntp;
  const bool active = tile < nt;
  const int lane = threadIdx.x & 63;
  const int m = lane & 15, quad = lane >> 4;

  floatx4 acc0 = {0.f,0.f,0.f,0.f};
  floatx4 acc1 = {0.f,0.f,0.f,0.f};

  if (active) {
    const int scls = __builtin_amdgcn_readfirstlane(tileclass[tile]);
    const int cz = scls/9, cy = (scls/3)%3, cx = scls%3;
    const int pid = sorted[tile*16 + m];
    const int pc  = pcoord[pid];
    const int bb = pc>>18, z = (pc>>12)&63, y = (pc>>6)&63, x = pc&63;
    const int linb = bb << 18;
    const int az[3] = { max(z-1,0)<<12, z<<12, min(z+1,DDIM-1)<<12 };
    const int ay[3] = { max(y-1,0)<<6,  y<<6,  min(y+1,DDIM-1)<<6 };
    const int ax[3] = { max(x-1,0),     x,     min(x+1,DDIM-1) };
    if (half == 0)
      accum_taps<0,14>(A, map, WT, cz,cy,cx, linb, az,ay,ax, m,quad, acc0,acc1);
    else
      accum_taps<14,27>(A, map, WT, cz,cy,cx, linb, az,ay,ax, m,quad, acc0,acc1);
  }

  if (active && half == 0) {
#pragma unroll
    for (int r = 0; r < 4; ++r) {
      red[tl][quad*4+r][m]    = acc0[r];
      red[tl][quad*4+r][m+16] = acc1[r];
    }
  }
  __syncthreads();
  if (active && half == 1) {
#pragma unroll
    for (int r = 0; r < 4; ++r) {
      acc0[r] += red[tl][quad*4+r][m];
      acc1[r] += red[tl][quad*4+r][m+16];
    }
    // D layout: col(N=cout) = lane&15, row(M=point) = quad*4 + reg
    const float bi0 = bias[m], bi1 = bias[m+16];
#pragma unroll
    for (int reg = 0; reg < 4; ++reg) {
      const int r  = quad*4 + reg;
      const int pr = sorted[tile*16 + r];
      if (pr >= NPTS) continue;            // padded lane
      const float mk = mask[pr];
      float v0 = (acc0[reg] + mk*bi0) * mk;
      float v1 = (acc1[reg] + mk*bi1) * mk;
      if (MODE == 0) {
        v0 = fmaxf(v0, 0.f); v1 = fmaxf(v1, 0.f);
        hout[pr*CCH + m]      = (_Float16)v0;
        hout[pr*CCH + m + 16] = (_Float16)v1;
      } else {
        fout[pr*CCH + m]      = resid[pr*CCH + m]      + v0;
        fout[pr*CCH + m + 16] = resid[pr*CCH + m + 16] + v1;
      }
    }
  }
}

// ---------------- launch ----------------

extern "C" void kernel_launch(void* const* d_in, const int* in_sizes, int n_in,
                              void* d_out, int out_size, void* d_ws, size_t ws_size,
                              hipStream_t stream) {
  const float* values = (const float*)d_in[0];
  const int*   indices= (const int*)  d_in[1];
  const float* maskv  = (const float*)d_in[2];
  const float* kern1  = (const float*)d_in[3];
  const float* bias1  = (const float*)d_in[4];
  const float* kern2  = (const float*)d_in[5];
  const float* bias2  = (const float*)d_in[6];
  float* out = (float*)d_out;

  char* ws = (char*)d_ws;
  size_t off = 0;
  auto alloc = [&](size_t bytes) { void* p = ws + off; off = (off + bytes + 255) & ~(size_t)255; return p; };
  int*      map      = (int*)     alloc(GVOX*4);            // 1 MB
  int*      pcoord   = (int*)     alloc((NPTS+1)*4);
  int*      cls      = (int*)     alloc(NPTS*4);
  int*      sorted   = (int*)     alloc(MAXTILES*16*4);
  int*      tileclass= (int*)     alloc(MAXTILES*4);
  int*      cnt      = (int*)     alloc(27*4);
  int*      slot     = (int*)     alloc(27*4);
  int*      ntiles   = (int*)     alloc(4);
  _Float16* valsh    = (_Float16*)alloc((NPTS+1)*CCH*2);    // 4 MB
  _Float16* hh       = (_Float16*)alloc((NPTS+1)*CCH*2);    // 4 MB
  _Float16* wt1      = (_Float16*)alloc(27*CCH*CCH*2);
  _Float16* wt2      = (_Float16*)alloc(27*CCH*CCH*2);

  k_prep0<<<(PREP0_THREADS + 255)/256, 256, 0, stream>>>(
      map, sorted, values, valsh, kern1, kern2, wt1, wt2, hh, pcoord, cnt, slot);
  k_prep1<<<NPTS/256, 256, 0, stream>>>(indices, map, pcoord, cls, cnt);
  k_prep3<<<NPTS/256 + (MAXTILES+255)/256, 256, 0, stream>>>(
      cls, cnt, slot, sorted, tileclass, ntiles);

  conv_mfma<0><<<MAXTILES/2, 256, 0, stream>>>(valsh, map, pcoord, sorted, tileclass,
                                               ntiles, wt1, bias1, maskv, nullptr, hh, nullptr);
  conv_mfma<1><<<MAXTILES/2, 256, 0, stream>>>(hh, map, pcoord, sorted, tileclass,
                                               ntiles, wt2, bias2, maskv, values, nullptr, out);
}